// Round 1
// baseline (100.001 us; speedup 1.0000x reference)
//
#include <hip/hip_runtime.h>

// QOuter: out_rr[b,i,j] = real[b,i]*real[b,j] + imag[b,i]*imag[b,j]
//         out_ii[b,i,j] = imag[b,i]*real[b,j] - real[b,i]*imag[b,j]
// B=64, N=1024. Outputs concatenated flat: [out_rr (B*N*N), out_ii (B*N*N)].
// Pure write-BW bound: 512 MiB stores/call, inputs 512 KB (cache-resident).

constexpr int B_ = 64;
constexpr int N_ = 1024;

__global__ __launch_bounds__(256) void qouter_kernel(
    const float* __restrict__ real,
    const float* __restrict__ imag,
    float* __restrict__ out) {
    const int bi = blockIdx.x;        // 0 .. B*N-1  (one block per output row)
    const int b  = bi >> 10;          // bi / N
    const int t  = threadIdx.x;       // 0..255 -> one float4 of the row

    // Broadcast scalars for this row (wave-uniform load, cache hit)
    const float rc = real[bi];        // real[b,i] since bi = b*N + i
    const float ic = imag[bi];

    // Row vectors real[b, 4t..4t+3], imag[b, 4t..4t+3] (L1/L2 resident)
    const float4 rj = reinterpret_cast<const float4*>(real + (size_t)b * N_)[t];
    const float4 ij = reinterpret_cast<const float4*>(imag + (size_t)b * N_)[t];

    float4 orr, oii;
    orr.x = rc * rj.x + ic * ij.x;
    orr.y = rc * rj.y + ic * ij.y;
    orr.z = rc * rj.z + ic * ij.z;
    orr.w = rc * rj.w + ic * ij.w;
    oii.x = ic * rj.x - rc * ij.x;
    oii.y = ic * rj.y - rc * ij.y;
    oii.z = ic * rj.z - rc * ij.z;
    oii.w = ic * rj.w - rc * ij.w;

    // float4 index into out_rr; out_ii is offset by B*N*N floats = B*N*N/4 float4s
    const size_t f4_rr = (size_t)bi * (N_ / 4) + t;
    const size_t f4_ii = f4_rr + (size_t)B_ * N_ * (N_ / 4);

    float4* out4 = reinterpret_cast<float4*>(out);
    out4[f4_rr] = orr;
    out4[f4_ii] = oii;
}

extern "C" void kernel_launch(void* const* d_in, const int* in_sizes, int n_in,
                              void* d_out, int out_size, void* d_ws, size_t ws_size,
                              hipStream_t stream) {
    const float* real = (const float*)d_in[0];
    const float* imag = (const float*)d_in[1];
    float* out = (float*)d_out;

    dim3 grid(B_ * N_);   // 65536 blocks, one per (b,i) row
    dim3 block(256);      // 256 threads x float4 = 1024 columns
    qouter_kernel<<<grid, block, 0, stream>>>(real, imag, out);
}